// Round 1
// baseline (116.613 us; speedup 1.0000x reference)
//
#include <hip/hip_runtime.h>

typedef unsigned short u16;
typedef unsigned int u32;
typedef __attribute__((ext_vector_type(8))) short bf16x8;
typedef __attribute__((ext_vector_type(8))) unsigned short u16x8;
typedef __attribute__((ext_vector_type(4))) float f32x4;

#define GLOBAL_AS __attribute__((address_space(1)))
#define LDS_AS __attribute__((address_space(3)))

#define BIGV 1.0e12f

__device__ __forceinline__ u16 f2bf(float f) {
  u32 u = __float_as_uint(f);
  u32 r = (u + 0x7fffu + ((u >> 16) & 1u)) >> 16;
  return (u16)r;
}
__device__ __forceinline__ float bf2f(u16 h) {
  return __uint_as_float(((u32)h) << 16);
}

__device__ __forceinline__ void comb(float& m1, float& s1, float m2, float s2) {
  float M = fmaxf(m1, m2);
  s1 = s1 * __expf(m1 - M) + s2 * __expf(m2 - M);
  m1 = M;
}

// ---------------- prep kernels ----------------

__global__ __launch_bounds__(256) void k_cvt_lhs(const float4* __restrict__ in,
                                                 ushort4* __restrict__ out) {
  int t = blockIdx.x * 256 + threadIdx.x;  // 1572864 total
  float4 v = in[t];
  ushort4 o;
  o.x = f2bf(v.x); o.y = f2bf(v.y); o.z = f2bf(v.z); o.w = f2bf(v.w);
  out[t] = o;
}

__global__ __launch_bounds__(256) void k_transpose_w(const float* __restrict__ W,
                                                     u16* __restrict__ WT) {
  __shared__ float tile[32][33];
  int tx = threadIdx.x, ty = threadIdx.y;             // (32,8)
  int gx = blockIdx.x * 32, gy = blockIdx.y * 32;     // gx: cols of W(1024), gy: rows (768)
  #pragma unroll
  for (int i = 0; i < 4; ++i)
    tile[ty + 8 * i][tx] = W[(size_t)(gy + ty + 8 * i) * 1024 + gx + tx];
  __syncthreads();
  #pragma unroll
  for (int i = 0; i < 4; ++i)
    WT[(size_t)(gx + ty + 8 * i) * 768 + gy + tx] = f2bf(tile[tx][ty + 8 * i]);
}

__global__ __launch_bounds__(256) void k_table(float2* __restrict__ tab) {
  int t = blockIdx.x * 256 + threadIdx.x;  // 16384 = 1024 pos * 16 freq
  int p = t >> 4, i = t & 15;
  float freq = __expf(-0.57564627324851148f * (float)i);  // ln(10000)/16
  float ang = (float)p * freq;
  float s, c;
  sincosf(ang, &s, &c);
  tab[t] = make_float2(s, c);
}

// ---------------- stage 1: proj = lhs @ W + b (bf16 MFMA, 128x128 tile, BK=64) ----------------

__global__ __launch_bounds__(256) void k_gemm1(const u16* __restrict__ A,   // [8192][768] bf16
                                               const u16* __restrict__ WT,  // [1024][768] bf16
                                               const float* __restrict__ bias,
                                               u16* __restrict__ qws,       // [128][512][64] bf16
                                               u16* __restrict__ kws) {
  __shared__ __align__(16) u16 As[128 * 64];
  __shared__ __align__(16) u16 Bs[128 * 64];
  const int tid = threadIdx.x;
  const int wave = tid >> 6, lane = tid & 63;
  const int lg = lane >> 4, lr = lane & 15;
  const int m0 = blockIdx.x * 128;
  const int e = blockIdx.y;
  const int n0 = e * 128;
  const int wr = wave >> 1, wc = wave & 1;

  f32x4 acc[4][4];
  #pragma unroll
  for (int i = 0; i < 4; ++i)
    #pragma unroll
    for (int j = 0; j < 4; ++j)
      acc[i][j] = (f32x4){0.f, 0.f, 0.f, 0.f};

  for (int k0 = 0; k0 < 768; k0 += 64) {
    // stage A and B tiles: each 128 rows x 64 bf16 = 1024 x 16B units, XOR-swizzled source
    #pragma unroll
    for (int i = 0; i < 4; ++i) {
      int u = (i * 4 + wave) * 64 + lane;
      int r = u >> 3, sl = u & 7;
      const u16* srcA = A + (size_t)(m0 + r) * 768 + k0 + ((sl ^ (r & 7)) * 8);
      __builtin_amdgcn_global_load_lds((const GLOBAL_AS void*)srcA,
                                       (LDS_AS void*)(As + (i * 4 + wave) * 512), 16, 0, 0);
      const u16* srcB = WT + (size_t)(n0 + r) * 768 + k0 + ((sl ^ (r & 7)) * 8);
      __builtin_amdgcn_global_load_lds((const GLOBAL_AS void*)srcB,
                                       (LDS_AS void*)(Bs + (i * 4 + wave) * 512), 16, 0, 0);
    }
    __syncthreads();
    #pragma unroll
    for (int ks = 0; ks < 2; ++ks) {
      bf16x8 af[4], bfr[4];
      #pragma unroll
      for (int mi = 0; mi < 4; ++mi) {
        int r = wr * 64 + mi * 16 + lr;
        int slot = (ks * 4 + lg) ^ (r & 7);
        af[mi] = *reinterpret_cast<const bf16x8*>(As + r * 64 + slot * 8);
      }
      #pragma unroll
      for (int ni = 0; ni < 4; ++ni) {
        int r = wc * 64 + ni * 16 + lr;
        int slot = (ks * 4 + lg) ^ (r & 7);
        bfr[ni] = *reinterpret_cast<const bf16x8*>(Bs + r * 64 + slot * 8);
      }
      #pragma unroll
      for (int mi = 0; mi < 4; ++mi)
        #pragma unroll
        for (int ni = 0; ni < 4; ++ni)
          acc[mi][ni] = __builtin_amdgcn_mfma_f32_16x16x32_bf16(af[mi], bfr[ni], acc[mi][ni], 0, 0, 0);
    }
    __syncthreads();
  }

  // epilogue: add bias, scatter into [be][s][d] bf16 (pre-RoPE)
  #pragma unroll
  for (int mi = 0; mi < 4; ++mi) {
    #pragma unroll
    for (int ni = 0; ni < 4; ++ni) {
      int nloc = wc * 64 + ni * 16 + lr;   // 0..127 within entity
      float bv = bias[n0 + nloc];
      int d = nloc & 63;
      u16* dst = (nloc < 64) ? qws : kws;
      #pragma unroll
      for (int q = 0; q < 4; ++q) {
        int m = m0 + wr * 64 + mi * 16 + lg * 4 + q;   // global row = b*512+s
        int bi = m >> 9, sdx = m & 511;
        float v = acc[mi][ni][q] + bv;
        dst[(((size_t)(bi * 8 + e) * 512 + sdx) << 6) + d] = f2bf(v);
      }
    }
  }
}

// ---------------- RoPE (in place on qws/kws) ----------------

__global__ __launch_bounds__(256) void k_rope(u16* __restrict__ qws, u16* __restrict__ kws,
                                              const int* __restrict__ bbox,
                                              const float2* __restrict__ tab) {
  int t = blockIdx.x * 256 + threadIdx.x;  // 1048576 = 2 * 65536 rows * 8 units
  int arr = t >> 19;
  int u = t & 524287;
  int rid = u >> 3;        // be*512 + s
  int d0 = (u & 7) * 8;
  int be = rid >> 9, s = rid & 511;
  int b = be >> 3;
  int x = bbox[((b << 9) + s) * 4 + 0];
  int y = bbox[((b << 9) + s) * 4 + 1];
  u16* base = (arr ? kws : qws) + ((size_t)rid << 6) + d0;
  u16x8 v = *reinterpret_cast<const u16x8*>(base);
  u16x8 o;
  #pragma unroll
  for (int j = 0; j < 8; j += 2) {
    int d = d0 + j;
    int pos = (d < 32) ? x : y;
    int fi = (d & 31) >> 1;
    float2 sc = tab[pos * 16 + fi];   // (sin, cos)
    float v0 = bf2f(v[j]), v1 = bf2f(v[j + 1]);
    o[j] = f2bf(v0 * sc.y - v1 * sc.x);
    o[j + 1] = f2bf(v1 * sc.y + v0 * sc.x);
  }
  *reinterpret_cast<u16x8*>(base) = o;
}

// ---------------- stage 2: logits + masked scaling + online-LSE loss partials ----------------

__global__ __launch_bounds__(256) void k_logits_loss(const u16* __restrict__ qws,
                                                     const u16* __restrict__ kws,
                                                     const int* __restrict__ mask,
                                                     const int* __restrict__ labels,
                                                     float* __restrict__ out,
                                                     float4* __restrict__ partials) {
  __shared__ __align__(16) u16 Qs[128 * 64];
  __shared__ __align__(16) u16 Ks[128 * 64];
  __shared__ float4 wred[4];
  const int tid = threadIdx.x;
  const int wave = tid >> 6, lane = tid & 63;
  const int lg = lane >> 4, lr = lane & 15;
  const int be = blockIdx.x, mb = blockIdx.y;
  const int b = be >> 3;
  const int m0 = mb * 128;

  const u16* qbase = qws + ((size_t)be * 512 + m0) * 64;
  const u16* kbase = kws + (size_t)be * 512 * 64;

  // stage Q block (128x64) once
  #pragma unroll
  for (int i = 0; i < 4; ++i) {
    int u = (i * 4 + wave) * 64 + lane;
    int r = u >> 3, sl = u & 7;
    const u16* src = qbase + r * 64 + ((sl ^ (r & 7)) * 8);
    __builtin_amdgcn_global_load_lds((const GLOBAL_AS void*)src,
                                     (LDS_AS void*)(Qs + (i * 4 + wave) * 512), 16, 0, 0);
  }

  float nm = -4e12f, ns = 0.f, pm = -4e12f, ps = 0.f;

  for (int cc = 0; cc < 4; ++cc) {
    // stage K/V rows cc*128 .. +128
    #pragma unroll
    for (int i = 0; i < 4; ++i) {
      int u = (i * 4 + wave) * 64 + lane;
      int r = u >> 3, sl = u & 7;
      const u16* src = kbase + (size_t)(cc * 128 + r) * 64 + ((sl ^ (r & 7)) * 8);
      __builtin_amdgcn_global_load_lds((const GLOBAL_AS void*)src,
                                       (LDS_AS void*)(Ks + (i * 4 + wave) * 512), 16, 0, 0);
    }
    __syncthreads();

    f32x4 acc[2][8];
    #pragma unroll
    for (int mi = 0; mi < 2; ++mi)
      #pragma unroll
      for (int ni = 0; ni < 8; ++ni)
        acc[mi][ni] = (f32x4){0.f, 0.f, 0.f, 0.f};

    #pragma unroll
    for (int ks = 0; ks < 2; ++ks) {
      bf16x8 a0, a1;
      {
        int r = wave * 32 + lr;
        int slot = (ks * 4 + lg) ^ (r & 7);
        a0 = *reinterpret_cast<const bf16x8*>(Qs + r * 64 + slot * 8);
      }
      {
        int r = wave * 32 + 16 + lr;
        int slot = (ks * 4 + lg) ^ (r & 7);
        a1 = *reinterpret_cast<const bf16x8*>(Qs + r * 64 + slot * 8);
      }
      #pragma unroll
      for (int ni = 0; ni < 8; ++ni) {
        int r = ni * 16 + lr;
        int slot = (ks * 4 + lg) ^ (r & 7);
        bf16x8 bv = *reinterpret_cast<const bf16x8*>(Ks + r * 64 + slot * 8);
        acc[0][ni] = __builtin_amdgcn_mfma_f32_16x16x32_bf16(a0, bv, acc[0][ni], 0, 0, 0);
        acc[1][ni] = __builtin_amdgcn_mfma_f32_16x16x32_bf16(a1, bv, acc[1][ni], 0, 0, 0);
      }
    }

    // epilogue: mask, tril, scale, write logits, accumulate online LSE
    #pragma unroll
    for (int mi = 0; mi < 2; ++mi) {
      #pragma unroll
      for (int ni = 0; ni < 8; ++ni) {
        int n = cc * 128 + ni * 16 + lr;
        float pad = (float)mask[(b << 9) + n];
        float mterm = (1.f - pad) * BIGV;
        #pragma unroll
        for (int q = 0; q < 4; ++q) {
          int m = m0 + wave * 32 + mi * 16 + lg * 4 + q;
          float L = acc[mi][ni][q] * pad - mterm;
          if (m > n) L -= BIGV;
          L *= 0.125f;
          size_t idx = (((size_t)be * 512) + m) * 512 + n;
          out[1 + idx] = L;
          float y = (float)labels[idx];
          float t1 = (1.f - 2.f * y) * L;
          float an = t1 - y * BIGV;
          float ap = t1 - (1.f - y) * BIGV;
          float M = fmaxf(nm, an);
          ns = ns * __expf(nm - M) + __expf(an - M);
          nm = M;
          M = fmaxf(pm, ap);
          ps = ps * __expf(pm - M) + __expf(ap - M);
          pm = M;
        }
      }
    }
    __syncthreads();
  }

  // wave reduce (max,sum) pairs
  #pragma unroll
  for (int off = 32; off > 0; off >>= 1) {
    float onm = __shfl_xor(nm, off), ons = __shfl_xor(ns, off);
    comb(nm, ns, onm, ons);
    float opm = __shfl_xor(pm, off), ops = __shfl_xor(ps, off);
    comb(pm, ps, opm, ops);
  }
  if (lane == 0) wred[wave] = make_float4(nm, ns, pm, ps);
  __syncthreads();
  if (tid == 0) {
    float4 r0 = wred[0];
    for (int w = 1; w < 4; ++w) {
      float4 rw = wred[w];
      comb(r0.x, r0.y, rw.x, rw.y);
      comb(r0.z, r0.w, rw.z, rw.w);
    }
    partials[be * 4 + mb] = r0;
  }
}

// ---------------- final: combine partials, mean, write loss ----------------

__global__ __launch_bounds__(128) void k_final(const float4* __restrict__ partials,
                                               float* __restrict__ out) {
  __shared__ float red[128];
  int t = threadIdx.x;  // = be
  float nm = -4e12f, ns = 0.f, pm = -4e12f, ps = 0.f;
  for (int mb = 0; mb < 4; ++mb) {
    float4 p = partials[t * 4 + mb];
    comb(nm, ns, p.x, p.y);
    comb(pm, ps, p.z, p.w);
  }
  comb(nm, ns, 0.f, 1.f);  // appended zero entry
  comb(pm, ps, 0.f, 1.f);
  float v = (nm + logf(ns)) + (pm + logf(ps));
  red[t] = v;
  __syncthreads();
  if (t == 0) {
    float s = 0.f;
    for (int i = 0; i < 128; ++i) s += red[i];
    out[0] = s * (1.f / 128.f);
  }
}

// ---------------- launch ----------------

extern "C" void kernel_launch(void* const* d_in, const int* in_sizes, int n_in,
                              void* d_out, int out_size, void* d_ws, size_t ws_size,
                              hipStream_t stream) {
  const float* lhs = (const float*)d_in[0];     // (16,512,768) f32
  const float* W = (const float*)d_in[1];       // (768,1024) f32
  const float* bias = (const float*)d_in[2];    // (1024,) f32
  const int* mask = (const int*)d_in[3];        // (16,512) i32
  const int* bbox = (const int*)d_in[4];        // (16,512,4) i32
  const int* labels = (const int*)d_in[5];      // (16,8,512,512) i32
  float* out = (float*)d_out;                   // [loss(1)] + logits (16,8,512,512) f32

  char* ws = (char*)d_ws;
  u16* lhsb = (u16*)(ws);                       // 12582912 B
  u16* wt = (u16*)(ws + 12582912);              // 1572864 B
  u16* qws = (u16*)(ws + 14155776);             // 8388608 B
  u16* kws = (u16*)(ws + 22544384);             // 8388608 B
  float2* tab = (float2*)(ws + 30932992);       // 131072 B
  float4* partials = (float4*)(ws + 31064064);  // 8192 B

  k_cvt_lhs<<<6144, 256, 0, stream>>>((const float4*)lhs, (ushort4*)lhsb);
  k_transpose_w<<<dim3(32, 24), dim3(32, 8), 0, stream>>>(W, wt);
  k_table<<<64, 256, 0, stream>>>(tab);
  k_gemm1<<<dim3(64, 8), 256, 0, stream>>>(lhsb, wt, bias, qws, kws);
  k_rope<<<4096, 256, 0, stream>>>(qws, kws, bbox, tab);
  k_logits_loss<<<dim3(128, 4), 256, 0, stream>>>(qws, kws, mask, labels, out, partials);
  k_final<<<1, 128, 0, stream>>>(partials, out);
}